// Round 10
// baseline (46.207 us; speedup 1.0000x reference)
//
#include <hip/hip_runtime.h>

// LIF forward over time-major x: (T=16, B=128, N=16384) fp32.
//   m[t] = 0.5*v[t-1] + x[t];  y[t] = (m >= 1.0);  v[t] = m*(1-y[t])
// R10: revert to R8 exactly (best passing config, 46.2 us):
//   - cached vector loads (LLC serves part of x across replays)
//   - sc0 sc1 nt stores: system-scope nontemporal -> zero write-allocate,
//     WRITE_SIZE exactly = y bytes
//   - one float4 column per thread, full T unroll, VGPR=8, occ 66%
// R9's 1-deep prefetch variant miscompiled (non-binary values in y:
// wrong register quad bound to the asm store input) and MLP probes
// (R4/R5/R7) were all null anyway -- this structure is the keeper.
// 268 MB logical / 46.2 us = 5.80 TB/s = 92% of m13 copy ceiling.

#define LIF_T 16
#define TAU 0.5f
#define VTH 1.0f

typedef float fx4 __attribute__((ext_vector_type(4)));

__global__ __launch_bounds__(256) void lif_fwd_kernel(
    const fx4* __restrict__ x, fx4* __restrict__ y, int cols) {
    int i = blockIdx.x * blockDim.x + threadIdx.x;
    if (i >= cols) return;

    fx4 v = {0.0f, 0.0f, 0.0f, 0.0f};
    size_t idx = (size_t)i;

#pragma unroll
    for (int t = 0; t < LIF_T; ++t) {
        fx4 xt = x[idx];

        fx4 m = v * TAU + xt;

        fx4 out;
        out.x = (m.x >= VTH) ? 1.0f : 0.0f;
        out.y = (m.y >= VTH) ? 1.0f : 0.0f;
        out.z = (m.z >= VTH) ? 1.0f : 0.0f;
        out.w = (m.w >= VTH) ? 1.0f : 0.0f;

        v.x = (m.x >= VTH) ? 0.0f : m.x;   // hard reset
        v.y = (m.y >= VTH) ? 0.0f : m.y;
        v.z = (m.z >= VTH) ? 0.0f : m.z;
        v.w = (m.w >= VTH) ? 0.0f : m.w;

        // system-scope nontemporal store: bypass all cache allocation.
        // No "memory" clobber: x/y don't alias; next loads may hoist.
        asm volatile("global_store_dwordx4 %0, %1, off sc0 sc1 nt"
                     :: "v"(&y[idx]), "v"(out));

        idx += (size_t)cols;
    }
}

extern "C" void kernel_launch(void* const* d_in, const int* in_sizes, int n_in,
                              void* d_out, int out_size, void* d_ws, size_t ws_size,
                              hipStream_t stream) {
    const fx4* x = (const fx4*)d_in[0];
    fx4* y = (fx4*)d_out;

    int total = in_sizes[0];
    int cols = total / LIF_T / 4;   // float4 columns per time plane

    const int block = 256;
    int grid = (cols + block - 1) / block;
    lif_fwd_kernel<<<grid, block, 0, stream>>>(x, y, cols);
}